// Round 12
// baseline (108.294 us; speedup 1.0000x reference)
//
#include <hip/hip_runtime.h>
#include <math.h>

#define N_PTS   65536
#define N_CTR   1024       // per set
#define NCELLS  256        // 16x16 Morton cells
#define CUT     40.0f      // cull: e < 2^-40 dropped (error < 5e-6 per output)
#define LOG2E   1.4426950408889634f
#define CPB     128        // centers per block (8 chunks per set)
#define MAXL    (CPB + 16)

#if __has_builtin(__builtin_amdgcn_exp2f)
#define EXP2(v) __builtin_amdgcn_exp2f(v)
#else
#define EXP2(v) exp2f(v)
#endif

__device__ __forceinline__ int morton4(int v) {
    v = (v | (v << 2)) & 0x33;
    v = (v | (v << 1)) & 0x55;
    return v;
}
__device__ __forceinline__ int cell_of(float2 p) {
    int cx = (int)(p.x * 16.f); cx = cx > 15 ? 15 : (cx < 0 ? 0 : cx);
    int cy = (int)(p.y * 16.f); cy = cy > 15 ? 15 : (cy < 0 ? 0 : cy);
    return morton4(cx) | (morton4(cy) << 1);
}

// K1: fold constants + count cells + zero staging buffer.
__global__ __launch_bounds__(256) void prep_kernel(
    const float* __restrict__ x,
    const float* __restrict__ h0, const float* __restrict__ c0, const float* __restrict__ w0,
    const float* __restrict__ h1, const float* __restrict__ c1, const float* __restrict__ w1,
    const float* __restrict__ h2, const float* __restrict__ c2, const float* __restrict__ w2,
    float4* __restrict__ RA, float4* __restrict__ RB, float* __restrict__ RC,
    float4* __restrict__ RT, unsigned int* __restrict__ cnt,
    float2* __restrict__ staged)
{
    const int idx = blockIdx.x * 256 + threadIdx.x;   // 0..65535
    {
        float2 z = make_float2(0.f, 0.f);
        staged[idx] = z; staged[idx + 65536] = z; staged[idx + 131072] = z;
        float2 p = ((const float2*)x)[idx];
        atomicAdd(&cnt[cell_of(p)], 1u);
    }
    if (idx >= 3 * N_CTR) return;

    const int set = idx >> 10;
    const int j   = idx & (N_CTR - 1);
    const float*  h = (set == 0) ? h0 : ((set == 1) ? h1 : h2);
    const float2* c = (const float2*)((set == 0) ? c0 : ((set == 1) ? c1 : c2));
    const float2* w = (const float2*)((set == 0) ? w0 : ((set == 1) ? w1 : w2));

    float2 cj = c[j];
    float2 wj = w[j];
    float  hh = h[j];
    float d1 = wj.x * wj.x;
    float d2 = wj.y * wj.y;
    float zb =  2.f * cj.x * d1 * LOG2E;
    float zc = -d1 * LOG2E;
    float zd =  2.f * cj.y * d2 * LOG2E;
    float ze = -d2 * LOG2E;
    float za = -(cj.x * cj.x * d1 + cj.y * cj.y * d2) * LOG2E;
    float k0, k1, k2, k3;
    if (set == 0) {
        k0 = -2.f * hh * d1;  k1 = 2.f * hh * d1 * cj.x;
        k2 = -2.f * hh * d2;  k3 = 2.f * hh * d2 * cj.y;
    } else if (set == 1) {
        k0 = hh;  k1 = -2.f * hh * d1;  k2 = 2.f * hh * d1 * cj.x;  k3 = 0.f;
    } else {
        k0 = hh;  k1 = -2.f * hh * d2;  k2 = 2.f * hh * d2 * cj.y;  k3 = 0.f;
    }
    RA[idx] = make_float4(zb, zc, zd, ze);
    RB[idx] = make_float4(za, k0, k1, k2);
    RC[idx] = k3;
    RT[idx] = make_float4(cj.x, cj.y, d1 * LOG2E, d2 * LOG2E);
}

// K2: exclusive prefix sum over 256 cells.
__global__ __launch_bounds__(256) void prefix_kernel(
    const unsigned int* __restrict__ cnt, unsigned int* __restrict__ cursor)
{
    __shared__ unsigned int s[256];
    const int t = threadIdx.x;
    unsigned int v = cnt[t];
    s[t] = v;
    __syncthreads();
    unsigned int acc = v;
    for (int off = 1; off < 256; off <<= 1) {
        unsigned int y = (t >= off) ? s[t - off] : 0u;
        __syncthreads();
        acc += y; s[t] = acc;
        __syncthreads();
    }
    cursor[t] = acc - v;
}

// K3: scatter to Morton-sorted order.
__global__ __launch_bounds__(256) void scatter_kernel(
    const float* __restrict__ x, unsigned int* __restrict__ cursor,
    unsigned short* __restrict__ sortedIdx)
{
    const int i = blockIdx.x * 256 + threadIdx.x;
    float2 p = ((const float2*)x)[i];
    unsigned int slot = atomicAdd(&cursor[cell_of(p)], 1u);
    sortedIdx[slot] = (unsigned short)i;
}

// K4: main. Block = (slice of 1024 sorted pts, set, 1/8 of centers).
// Cull 128 centers vs slice bbox -> LDS-compacted, zero-padded to x16;
// R10's proven dense schedule on the live list; coalesced staged atomics.
__global__ __launch_bounds__(256) void srbf_main(
    const float* __restrict__ x,
    const float4* __restrict__ RA, const float4* __restrict__ RB,
    const float*  __restrict__ RC, const float4* __restrict__ RT,
    const unsigned short* __restrict__ sortedIdx,
    float* __restrict__ staged)
{
    __shared__ float4 sA[MAXL];
    __shared__ float4 sK[MAXL];
    __shared__ float  sk3[MAXL];
    __shared__ int    wtot[4];
    __shared__ float4 bbx[4];

    const int bid   = blockIdx.x;        // 0..1535  (6/CU, 6 waves/SIMD)
    const int slice = bid / 24;
    const int rr    = bid % 24;
    const int set   = rr >> 3;
    const int q     = rr & 7;
    const int tid   = threadIdx.x;
    const int lane  = tid & 63;
    const int wv    = tid >> 6;
    const int cbase = set * N_CTR + q * CPB;

    // ---- 4 points (sorted order) ----
    const float2* xp = (const float2*)x;
    const int sbase = slice * 1024 + tid;
    float X[4], Y[4];
    #pragma unroll
    for (int k = 0; k < 4; ++k) {
        int o = sortedIdx[sbase + k * 256];
        float2 p = xp[o];
        X[k] = p.x; Y[k] = p.y;
    }

    // ---- slice bbox ----
    float mnx = fminf(fminf(X[0], X[1]), fminf(X[2], X[3]));
    float mxx = fmaxf(fmaxf(X[0], X[1]), fmaxf(X[2], X[3]));
    float mny = fminf(fminf(Y[0], Y[1]), fminf(Y[2], Y[3]));
    float mxy = fmaxf(fmaxf(Y[0], Y[1]), fmaxf(Y[2], Y[3]));
    #pragma unroll
    for (int d = 1; d < 64; d <<= 1) {
        mnx = fminf(mnx, __shfl_xor(mnx, d));
        mxx = fmaxf(mxx, __shfl_xor(mxx, d));
        mny = fminf(mny, __shfl_xor(mny, d));
        mxy = fmaxf(mxy, __shfl_xor(mxy, d));
    }
    if (lane == 0) bbx[wv] = make_float4(mnx, mxx, mny, mxy);
    __syncthreads();
    {
        float4 b0 = bbx[0], b1 = bbx[1], b2 = bbx[2], b3 = bbx[3];
        mnx = fminf(fminf(b0.x, b1.x), fminf(b2.x, b3.x));
        mxx = fmaxf(fmaxf(b0.y, b1.y), fmaxf(b2.y, b3.y));
        mny = fminf(fminf(b0.z, b1.z), fminf(b2.z, b3.z));
        mxy = fmaxf(fmaxf(b0.w, b1.w), fmaxf(b2.w, b3.w));
    }

    // ---- cull 128 centers (waves 0,1), compact into LDS ----
    bool live = false;
    if (tid < CPB) {
        float4 T = RT[cbase + tid];
        float dxm = fmaxf(fmaxf(mnx - T.x, T.x - mxx), 0.f);
        float dym = fmaxf(fmaxf(mny - T.y, T.y - mxy), 0.f);
        live = (dxm * dxm * T.z + dym * dym * T.w) < CUT;
    }
    unsigned long long mask = __ballot(live);
    if (lane == 0) wtot[wv] = __popcll(mask);
    __syncthreads();
    int base = 0, m = 0;
    #pragma unroll
    for (int w2 = 0; w2 < 4; ++w2) {
        int t = wtot[w2];
        m += t;
        if (w2 < wv) base += t;
    }
    if (live) {
        int p = base + __popcll(mask & ((1ull << lane) - 1ull));
        sA[p] = RA[cbase + tid]; sK[p] = RB[cbase + tid]; sk3[p] = RC[cbase + tid];
    }
    const int mPad = (m + 15) & ~15;
    if (tid < mPad - m) {   // zero-pad: e=exp2(0)=1 times k=0 -> contributes 0
        sA[m + tid]  = make_float4(0.f, 0.f, 0.f, 0.f);
        sK[m + tid]  = make_float4(0.f, 0.f, 0.f, 0.f);
        sk3[m + tid] = 0.f;
    }
    __syncthreads();

    // ---- live-center loop: compile-time 16-body, runtime trip count ----
    float A0[4], A1[4], A2[4], A3[4];
    #pragma unroll
    for (int k = 0; k < 4; ++k) { A0[k] = A1[k] = A2[k] = A3[k] = 0.f; }

    for (int t = 0; t < mPad; t += 16) {
        #pragma unroll
        for (int u = 0; u < 16; ++u) {
            const float4 A  = sA[t + u];
            const float4 K  = sK[t + u];
            const float  k3 = sk3[t + u];
            float e[4];
            #pragma unroll
            for (int k = 0; k < 4; ++k) {
                float t1 = fmaf(X[k], A.y, A.x);
                float t2 = fmaf(X[k], t1,  K.x);
                float t3 = fmaf(Y[k], A.w, A.z);
                float s  = fmaf(Y[k], t3,  t2);
                e[k] = EXP2(s);
            }
            #pragma unroll
            for (int k = 0; k < 4; ++k) {
                A0[k] = fmaf(K.y, e[k], A0[k]);
                A1[k] = fmaf(K.z, e[k], A1[k]);
                A2[k] = fmaf(K.w, e[k], A2[k]);
                A3[k] = fmaf(k3,  e[k], A3[k]);
            }
        }
    }

    // ---- coalesced staged atomics (sorted-position layout) ----
    float* st = staged + (size_t)set * 2 * N_PTS;
    #pragma unroll
    for (int k = 0; k < 4; ++k) {
        const int sp = sbase + k * 256;
        float r1, r2;
        if (set == 0)      { r1 = fmaf(X[k], A0[k], A1[k]); r2 = fmaf(Y[k], A2[k], A3[k]); }
        else if (set == 1) { r1 = A0[k];                    r2 = fmaf(X[k], A1[k], A2[k]); }
        else               { r1 = A0[k];                    r2 = fmaf(Y[k], A1[k], A2[k]); }
        atomicAdd(&st[sp * 2],     r1);   // contiguous per lane -> coalesced
        atomicAdd(&st[sp * 2 + 1], r2);
    }
}

// K5: permute staged (sorted order) -> out (original order), plain stores.
__global__ __launch_bounds__(256) void gather_kernel(
    const float2* __restrict__ staged,
    const unsigned short* __restrict__ sortedIdx,
    float* __restrict__ out)
{
    const int sp = blockIdx.x * 256 + threadIdx.x;   // sorted position
    const int o  = sortedIdx[sp];
    #pragma unroll
    for (int set = 0; set < 3; ++set) {
        float2 v = staged[set * N_PTS + sp];
        float* ob = out + (size_t)set * 2 * N_PTS;
        ob[o]         = v.x;
        ob[N_PTS + o] = v.y;
    }
}

extern "C" void kernel_launch(void* const* d_in, const int* in_sizes, int n_in,
                              void* d_out, int out_size, void* d_ws, size_t ws_size,
                              hipStream_t stream) {
    const float* x  = (const float*)d_in[0];
    const float* h1 = (const float*)d_in[1];
    const float* c1 = (const float*)d_in[2];
    const float* w1 = (const float*)d_in[3];
    const float* h2 = (const float*)d_in[4];
    const float* c2 = (const float*)d_in[5];
    const float* w2 = (const float*)d_in[6];
    const float* h3 = (const float*)d_in[7];
    const float* c3 = (const float*)d_in[8];
    const float* w3 = (const float*)d_in[9];

    char* ws = (char*)d_ws;
    float4* RA = (float4*)(ws);                               // 49152 B
    float4* RB = (float4*)(ws + 49152);                       // 49152 B
    float*  RC = (float*) (ws + 98304);                       // 12288 B
    float4* RT = (float4*)(ws + 110592);                      // 49152 B
    unsigned int*   cnt    = (unsigned int*)(ws + 159744);    // 1024 B
    unsigned int*   cursor = (unsigned int*)(ws + 160768);    // 1024 B
    unsigned short* sidx   = (unsigned short*)(ws + 161792);  // 131072 B
    float* staged = (float*)(ws + 292864);                    // 1572864 B (~1.87 MB total)

    hipMemsetAsync(cnt, 0, NCELLS * sizeof(unsigned int), stream);

    prep_kernel<<<dim3(256), dim3(256), 0, stream>>>(
        x, h1, c1, w1, h2, c2, w2, h3, c3, w3, RA, RB, RC, RT, cnt, (float2*)staged);

    prefix_kernel<<<dim3(1), dim3(256), 0, stream>>>(cnt, cursor);

    scatter_kernel<<<dim3(256), dim3(256), 0, stream>>>(x, cursor, sidx);

    // 64 slices x 3 sets x 8 center-chunks = 1536 blocks (6/CU, 6 waves/SIMD)
    srbf_main<<<dim3(1536), dim3(256), 0, stream>>>(
        x, RA, RB, RC, RT, sidx, staged);

    gather_kernel<<<dim3(256), dim3(256), 0, stream>>>(
        (const float2*)staged, sidx, (float*)d_out);
}

// Round 13
// 79.090 us; speedup vs baseline: 1.3692x; 1.3692x over previous
//
#include <hip/hip_runtime.h>
#include <math.h>

#define N_PTS   65536
#define N_CTR   1024
#define NCELLS  256        // 16x16 geometric cells
#define SLOTS   256        // per-cell slots handled by main (n_mean = 256)
#define OCAP    4096       // overflow list capacity (expected ~1.6K)
#define CUT     40.0f      // drop e < 2^-40 (error < 1e-5 per output)
#define LOG2E   1.4426950408889634f
#define MAXL    (N_CTR + 16)

#if __has_builtin(__builtin_amdgcn_exp2f)
#define EXP2(v) __builtin_amdgcn_exp2f(v)
#else
#define EXP2(v) exp2f(v)
#endif

struct Fold { float4 A; float4 K; float k3; };

__device__ __forceinline__ Fold fold_center(int set, float2 cj, float2 wj, float hh) {
    float d1 = wj.x * wj.x, d2 = wj.y * wj.y;
    Fold f;
    f.A = make_float4(2.f * cj.x * d1 * LOG2E, -d1 * LOG2E,
                      2.f * cj.y * d2 * LOG2E, -d2 * LOG2E);
    float za = -(cj.x * cj.x * d1 + cj.y * cj.y * d2) * LOG2E;
    float k0, k1, k2, k3;
    if (set == 0) {
        k0 = -2.f * hh * d1;  k1 = 2.f * hh * d1 * cj.x;
        k2 = -2.f * hh * d2;  k3 = 2.f * hh * d2 * cj.y;
    } else if (set == 1) {
        k0 = hh;  k1 = -2.f * hh * d1;  k2 = 2.f * hh * d1 * cj.x;  k3 = 0.f;
    } else {
        k0 = hh;  k1 = -2.f * hh * d2;  k2 = 2.f * hh * d2 * cj.y;  k3 = 0.f;
    }
    f.K = make_float4(za, k0, k1, k2);
    f.k3 = k3;
    return f;
}

__global__ __launch_bounds__(256) void zero_kernel(unsigned int* __restrict__ cnt,
                                                   unsigned int* __restrict__ ocnt) {
    cnt[threadIdx.x] = 0u;
    if (threadIdx.x == 0) *ocnt = 0u;
}

__global__ __launch_bounds__(256) void bucket_kernel(
    const float* __restrict__ x, unsigned int* __restrict__ cnt,
    unsigned short* __restrict__ idxl,
    unsigned int* __restrict__ ocnt, unsigned short* __restrict__ olist)
{
    const int i = blockIdx.x * 256 + threadIdx.x;
    float2 p = ((const float2*)x)[i];
    int cx = (int)(p.x * 16.f); cx = cx > 15 ? 15 : (cx < 0 ? 0 : cx);
    int cy = (int)(p.y * 16.f); cy = cy > 15 ? 15 : (cy < 0 ? 0 : cy);
    const int cell = cy * 16 + cx;
    unsigned int slot = atomicAdd(&cnt[cell], 1u);
    if (slot < SLOTS) {
        idxl[cell * SLOTS + slot] = (unsigned short)i;
    } else {
        unsigned int os = atomicAdd(ocnt, 1u);
        if (os < OCAP) olist[os] = (unsigned short)i;
    }
}

// Main: block = (cell, set). Fold+cull 1024 centers vs cell bounds inline,
// compact live into LDS (padded x16), PPT=1 dense inner loop, plain stores.
__global__ __launch_bounds__(256) void srbf_main(
    const float* __restrict__ x,
    const float* __restrict__ h0, const float* __restrict__ c0, const float* __restrict__ w0,
    const float* __restrict__ h1, const float* __restrict__ c1, const float* __restrict__ w1,
    const float* __restrict__ h2, const float* __restrict__ c2, const float* __restrict__ w2,
    const unsigned int* __restrict__ cnt, const unsigned short* __restrict__ idxl,
    float* __restrict__ out)
{
    __shared__ float4 sA[MAXL];
    __shared__ float4 sK[MAXL];
    __shared__ float  sk3[MAXL];
    __shared__ int    wtot[4];

    const int bid  = blockIdx.x;        // 0..767
    const int set  = bid >> 8;
    const int cell = bid & 255;
    const int tid  = threadIdx.x;
    const int lane = tid & 63;
    const int wv   = tid >> 6;

    const float*  h = (set == 0) ? h0 : ((set == 1) ? h1 : h2);
    const float2* c = (const float2*)((set == 0) ? c0 : ((set == 1) ? c1 : c2));
    const float2* w = (const float2*)((set == 0) ? w0 : ((set == 1) ? w1 : w2));

    const float cx0 = (float)(cell & 15) * 0.0625f;
    const float cy0 = (float)(cell >> 4) * 0.0625f;
    const float cx1 = cx0 + 0.0625f;
    const float cy1 = cy0 + 0.0625f;

    // ---- fold + cull 4 centers per thread (one barrier total) ----
    bool lv[4];
    Fold f[4];
    unsigned long long mk[4];
    #pragma unroll
    for (int r = 0; r < 4; ++r) {
        const int j = r * 256 + tid;
        float2 cj = c[j], wj = w[j];
        float  hh = h[j];
        float d1 = wj.x * wj.x, d2 = wj.y * wj.y;
        float dxm = fmaxf(fmaxf(cx0 - cj.x, cj.x - cx1), 0.f);
        float dym = fmaxf(fmaxf(cy0 - cj.y, cj.y - cy1), 0.f);
        lv[r] = (dxm * dxm * d1 + dym * dym * d2) * LOG2E < CUT;
        f[r] = fold_center(set, cj, wj, hh);
    }
    #pragma unroll
    for (int r = 0; r < 4; ++r) mk[r] = __ballot(lv[r]);
    int wsum = __popcll(mk[0]) + __popcll(mk[1]) + __popcll(mk[2]) + __popcll(mk[3]);
    if (lane == 0) wtot[wv] = wsum;
    __syncthreads();
    int base = 0, m = 0;
    #pragma unroll
    for (int q2 = 0; q2 < 4; ++q2) {
        int t = wtot[q2];
        m += t;
        if (q2 < wv) base += t;
    }
    const unsigned long long lt = (1ull << lane) - 1ull;
    int roff = 0;
    #pragma unroll
    for (int r = 0; r < 4; ++r) {
        if (lv[r]) {
            int pos = base + roff + __popcll(mk[r] & lt);
            sA[pos] = f[r].A; sK[pos] = f[r].K; sk3[pos] = f[r].k3;
        }
        roff += __popcll(mk[r]);
    }
    const int mPad = (m + 15) & ~15;
    if (tid < mPad - m) {   // zero-pad: e=exp2(0)=1, k=0 -> contributes 0
        sA[m + tid]  = make_float4(0.f, 0.f, 0.f, 0.f);
        sK[m + tid]  = make_float4(0.f, 0.f, 0.f, 0.f);
        sk3[m + tid] = 0.f;
    }

    // ---- this thread's point ----
    const int n = min((int)cnt[cell], SLOTS);
    const bool valid = tid < n;
    int o = 0; float X = 0.5f, Y = 0.5f;
    if (valid) {
        o = idxl[cell * SLOTS + tid];
        float2 p = ((const float2*)x)[o];
        X = p.x; Y = p.y;
    }
    __syncthreads();

    // ---- live-center loop (unroll 16, compile-time body) ----
    float A0 = 0.f, A1 = 0.f, A2 = 0.f, A3 = 0.f;
    if (set == 0) {
        for (int t = 0; t < mPad; t += 16) {
            #pragma unroll
            for (int u = 0; u < 16; ++u) {
                float4 A = sA[t + u]; float4 K = sK[t + u]; float k3 = sk3[t + u];
                float t1 = fmaf(X, A.y, A.x);
                float t2 = fmaf(X, t1,  K.x);
                float t3 = fmaf(Y, A.w, A.z);
                float s  = fmaf(Y, t3,  t2);
                float e  = EXP2(s);
                A0 = fmaf(K.y, e, A0); A1 = fmaf(K.z, e, A1);
                A2 = fmaf(K.w, e, A2); A3 = fmaf(k3,  e, A3);
            }
        }
    } else {
        for (int t = 0; t < mPad; t += 16) {
            #pragma unroll
            for (int u = 0; u < 16; ++u) {
                float4 A = sA[t + u]; float4 K = sK[t + u];
                float t1 = fmaf(X, A.y, A.x);
                float t2 = fmaf(X, t1,  K.x);
                float t3 = fmaf(Y, A.w, A.z);
                float s  = fmaf(Y, t3,  t2);
                float e  = EXP2(s);
                A0 = fmaf(K.y, e, A0); A1 = fmaf(K.z, e, A1);
                A2 = fmaf(K.w, e, A2);
            }
        }
    }

    if (valid) {
        float* ob = out + (size_t)set * 2 * N_PTS;
        float r1, r2;
        if (set == 0)      { r1 = fmaf(X, A0, A1); r2 = fmaf(Y, A2, A3); }
        else if (set == 1) { r1 = A0;              r2 = fmaf(X, A1, A2); }
        else               { r1 = A0;              r2 = fmaf(Y, A1, A2); }
        ob[o]         = r1;   // complete sum, plain store (L2-resident)
        ob[N_PTS + o] = r2;
    }
}

// Overflow: dense 1024-center sum for spilled points (~1.6K expected).
// Block = (set, 64 points); thread (lane=point, wave=center-quarter).
__global__ __launch_bounds__(256) void overflow_kernel(
    const float* __restrict__ x,
    const float* __restrict__ h0, const float* __restrict__ c0, const float* __restrict__ w0,
    const float* __restrict__ h1, const float* __restrict__ c1, const float* __restrict__ w1,
    const float* __restrict__ h2, const float* __restrict__ c2, const float* __restrict__ w2,
    const unsigned int* __restrict__ ocnt, const unsigned short* __restrict__ olist,
    float* __restrict__ out)
{
    __shared__ float4 sA[N_CTR];
    __shared__ float4 sK[N_CTR];
    __shared__ float  sk3[N_CTR];
    __shared__ float  red[4][64][4];

    const int bid = blockIdx.x;           // 0..191
    const int set = bid >> 6;             // 64 blocks per set
    const int blk = bid & 63;
    const int tid = threadIdx.x;
    const int lane = tid & 63;
    const int q    = tid >> 6;

    int oc = (int)*ocnt;
    oc = oc < OCAP ? oc : OCAP;
    const int pbase = blk * 64;
    if (pbase >= oc) return;              // uniform early exit (most blocks)

    const float*  h = (set == 0) ? h0 : ((set == 1) ? h1 : h2);
    const float2* c = (const float2*)((set == 0) ? c0 : ((set == 1) ? c1 : c2));
    const float2* w = (const float2*)((set == 0) ? w0 : ((set == 1) ? w1 : w2));

    #pragma unroll
    for (int r = 0; r < 4; ++r) {
        const int j = r * 256 + tid;
        Fold f = fold_center(set, c[j], w[j], h[j]);
        sA[j] = f.A; sK[j] = f.K; sk3[j] = f.k3;
    }
    __syncthreads();

    const bool valid = (pbase + lane) < oc;
    int o = 0; float X = 0.5f, Y = 0.5f;
    if (valid) {
        o = olist[pbase + lane];
        float2 p = ((const float2*)x)[o];
        X = p.x; Y = p.y;
    }

    float A0 = 0.f, A1 = 0.f, A2 = 0.f, A3 = 0.f;
    const int cb = q * 256;
    for (int t = 0; t < 256; t += 8) {
        #pragma unroll
        for (int u = 0; u < 8; ++u) {
            float4 A = sA[cb + t + u]; float4 K = sK[cb + t + u]; float k3 = sk3[cb + t + u];
            float t1 = fmaf(X, A.y, A.x);
            float t2 = fmaf(X, t1,  K.x);
            float t3 = fmaf(Y, A.w, A.z);
            float s  = fmaf(Y, t3,  t2);
            float e  = EXP2(s);
            A0 = fmaf(K.y, e, A0); A1 = fmaf(K.z, e, A1);
            A2 = fmaf(K.w, e, A2); A3 = fmaf(k3,  e, A3);
        }
    }
    red[q][lane][0] = A0; red[q][lane][1] = A1;
    red[q][lane][2] = A2; red[q][lane][3] = A3;
    __syncthreads();

    if (q == 0 && valid) {
        A0 = red[0][lane][0] + red[1][lane][0] + red[2][lane][0] + red[3][lane][0];
        A1 = red[0][lane][1] + red[1][lane][1] + red[2][lane][1] + red[3][lane][1];
        A2 = red[0][lane][2] + red[1][lane][2] + red[2][lane][2] + red[3][lane][2];
        A3 = red[0][lane][3] + red[1][lane][3] + red[2][lane][3] + red[3][lane][3];
        float* ob = out + (size_t)set * 2 * N_PTS;
        float r1, r2;
        if (set == 0)      { r1 = fmaf(X, A0, A1); r2 = fmaf(Y, A2, A3); }
        else if (set == 1) { r1 = A0;              r2 = fmaf(X, A1, A2); }
        else               { r1 = A0;              r2 = fmaf(Y, A1, A2); }
        ob[o]         = r1;
        ob[N_PTS + o] = r2;
    }
}

extern "C" void kernel_launch(void* const* d_in, const int* in_sizes, int n_in,
                              void* d_out, int out_size, void* d_ws, size_t ws_size,
                              hipStream_t stream) {
    const float* x  = (const float*)d_in[0];
    const float* h1 = (const float*)d_in[1];
    const float* c1 = (const float*)d_in[2];
    const float* w1 = (const float*)d_in[3];
    const float* h2 = (const float*)d_in[4];
    const float* c2 = (const float*)d_in[5];
    const float* w2 = (const float*)d_in[6];
    const float* h3 = (const float*)d_in[7];
    const float* c3 = (const float*)d_in[8];
    const float* w3 = (const float*)d_in[9];

    char* ws = (char*)d_ws;
    unsigned int*   cnt   = (unsigned int*)(ws);            // 1024 B
    unsigned int*   ocnt  = (unsigned int*)(ws + 1024);     // 4 B
    unsigned short* olist = (unsigned short*)(ws + 2048);   // 8192 B
    unsigned short* idxl  = (unsigned short*)(ws + 10240);  // 131072 B (total ~138 KB)

    zero_kernel<<<dim3(1), dim3(256), 0, stream>>>(cnt, ocnt);

    bucket_kernel<<<dim3(256), dim3(256), 0, stream>>>(x, cnt, idxl, ocnt, olist);

    // 256 cells x 3 sets = 768 blocks (3/CU exact)
    srbf_main<<<dim3(768), dim3(256), 0, stream>>>(
        x, h1, c1, w1, h2, c2, w2, h3, c3, w3, cnt, idxl, (float*)d_out);

    overflow_kernel<<<dim3(192), dim3(256), 0, stream>>>(
        x, h1, c1, w1, h2, c2, w2, h3, c3, w3, ocnt, olist, (float*)d_out);
}

// Round 14
// 56.316 us; speedup vs baseline: 1.9230x; 1.4044x over previous
//
#include <hip/hip_runtime.h>
#include <math.h>

#define N_PTS  65536
#define N_CTR  1024
#define CHUNK  128          // centers per block -> 8 chunks per set
#define PPT    8            // points per thread (ILP for exp-latency hiding)
#define PPB    (256 * PPT)  // 2048 points per block
#define LOG2E  1.4426950408889634f

#if __has_builtin(__builtin_amdgcn_exp2f)
#define EXP2(v) __builtin_amdgcn_exp2f(v)
#else
#define EXP2(v) exp2f(v)
#endif

// R10 (52.3us, VALUBusy 78%, busy-time 40.5us = issue floor) with one change:
// PPT 4 -> 8. Doubles per-wave independent chains (8 poly->exp->acc streams)
// to close the 22% issue-idle from exp/dependency bubbles.
// __launch_bounds__(256,4) gives the allocator a 128-VGPR budget so the
// ~85-reg state fits WITHOUT rematerialization (R2's PPT=8 failure mode was
// the default occupancy-greedy 52-VGPR cap).
// Grid: 3 sets x 8 chunks x 32 point-blocks = 768 blocks = 3/CU exact.
// Horner: s = (za + x*(zb+zc*x)) + y*(zd+ze*y); e = exp2(s)
// set0: ux = x*S(k0 e)+S(k1 e), uy = y*S(k2 e)+S(k3 e)
// set1: P = S(k0 e), Px = x*S(k1 e)+S(k2 e);  set2: Q,Qy analog.
__global__ __launch_bounds__(256, 4) void srbf_main(
    const float* __restrict__ x,
    const float* __restrict__ h0, const float* __restrict__ c0, const float* __restrict__ w0,
    const float* __restrict__ h1, const float* __restrict__ c1, const float* __restrict__ w1,
    const float* __restrict__ h2, const float* __restrict__ c2, const float* __restrict__ w2,
    float* __restrict__ out)
{
    __shared__ float4 sA[CHUNK];   // (zb, zc, zd, ze)
    __shared__ float4 sK[CHUNK];   // (za, k0, k1, k2)
    __shared__ float  sk3[CHUNK];  // k3

    const int bid   = blockIdx.x;        // 0..767
    const int set   = bid >> 8;          // 256 blocks per set
    const int r     = bid & 255;
    const int chunk = r >> 5;            // 8 chunks of 128 centers
    const int pblk  = r & 31;            // 32 point-blocks of 2048 points
    const int tid   = threadIdx.x;

    // ---- inline constant fold: 128 threads, one center each ----
    if (tid < CHUNK) {
        const int j = chunk * CHUNK + tid;
        const float*  h = (set == 0) ? h0 : ((set == 1) ? h1 : h2);
        const float2* c = (const float2*)((set == 0) ? c0 : ((set == 1) ? c1 : c2));
        const float2* w = (const float2*)((set == 0) ? w0 : ((set == 1) ? w1 : w2));
        float2 cj = c[j];
        float2 wj = w[j];
        float  hh = h[j];
        float d1 = wj.x * wj.x;
        float d2 = wj.y * wj.y;
        float zb =  2.f * cj.x * d1 * LOG2E;
        float zc = -d1 * LOG2E;
        float zd =  2.f * cj.y * d2 * LOG2E;
        float ze = -d2 * LOG2E;
        float za = -(cj.x * cj.x * d1 + cj.y * cj.y * d2) * LOG2E;
        float k0, k1, k2, k3;
        if (set == 0) {
            k0 = -2.f * hh * d1;  k1 = 2.f * hh * d1 * cj.x;
            k2 = -2.f * hh * d2;  k3 = 2.f * hh * d2 * cj.y;
        } else if (set == 1) {
            k0 = hh;  k1 = -2.f * hh * d1;  k2 = 2.f * hh * d1 * cj.x;  k3 = 0.f;
        } else {
            k0 = hh;  k1 = -2.f * hh * d2;  k2 = 2.f * hh * d2 * cj.y;  k3 = 0.f;
        }
        sA[tid]  = make_float4(zb, zc, zd, ze);
        sK[tid]  = make_float4(za, k0, k1, k2);
        sk3[tid] = k3;
    }

    // ---- load 8 points while constants fold ----
    const int base = pblk * PPB + tid;
    float X[PPT], Y[PPT];
    #pragma unroll
    for (int p = 0; p < PPT; ++p) {
        float2 q = ((const float2*)x)[base + p * 256];
        X[p] = q.x;  Y[p] = q.y;
    }
    __syncthreads();

    if (set == 0) {
        float A0[PPT], A1[PPT], A2[PPT], A3[PPT];
        #pragma unroll
        for (int p = 0; p < PPT; ++p) { A0[p] = A1[p] = A2[p] = A3[p] = 0.f; }

        #pragma unroll 2
        for (int j = 0; j < CHUNK; ++j) {
            const float4 A  = sA[j];    // broadcast ds_read -> VGPRs
            const float4 K  = sK[j];
            const float  k3 = sk3[j];
            float e[PPT];
            #pragma unroll
            for (int p = 0; p < PPT; ++p) {
                float t1 = fmaf(X[p], A.y, A.x);   // zb + zc*x
                float t2 = fmaf(X[p], t1,  K.x);   // za + x*(...)
                float t3 = fmaf(Y[p], A.w, A.z);   // zd + ze*y
                float s  = fmaf(Y[p], t3,  t2);
                e[p] = EXP2(s);
            }
            #pragma unroll
            for (int p = 0; p < PPT; ++p) {
                A0[p] = fmaf(K.y, e[p], A0[p]);
                A1[p] = fmaf(K.z, e[p], A1[p]);
                A2[p] = fmaf(K.w, e[p], A2[p]);
                A3[p] = fmaf(k3,  e[p], A3[p]);
            }
        }
        #pragma unroll
        for (int p = 0; p < PPT; ++p) {
            const int i = base + p * 256;
            atomicAdd(&out[i],         fmaf(X[p], A0[p], A1[p]));   // ux
            atomicAdd(&out[N_PTS + i], fmaf(Y[p], A2[p], A3[p]));   // uy
        }
    } else {
        float A0[PPT], A1[PPT], A2[PPT];
        #pragma unroll
        for (int p = 0; p < PPT; ++p) { A0[p] = A1[p] = A2[p] = 0.f; }

        #pragma unroll 2
        for (int j = 0; j < CHUNK; ++j) {
            const float4 A = sA[j];
            const float4 K = sK[j];
            float e[PPT];
            #pragma unroll
            for (int p = 0; p < PPT; ++p) {
                float t1 = fmaf(X[p], A.y, A.x);
                float t2 = fmaf(X[p], t1,  K.x);
                float t3 = fmaf(Y[p], A.w, A.z);
                float s  = fmaf(Y[p], t3,  t2);
                e[p] = EXP2(s);
            }
            #pragma unroll
            for (int p = 0; p < PPT; ++p) {
                A0[p] = fmaf(K.y, e[p], A0[p]);
                A1[p] = fmaf(K.z, e[p], A1[p]);
                A2[p] = fmaf(K.w, e[p], A2[p]);
            }
        }
        float* o = out + (size_t)set * 2 * N_PTS;
        #pragma unroll
        for (int p = 0; p < PPT; ++p) {
            const int i = base + p * 256;
            const float g = (set == 1) ? X[p] : Y[p];
            atomicAdd(&o[i],         A0[p]);                  // P or Q
            atomicAdd(&o[N_PTS + i], fmaf(g, A1[p], A2[p]));  // Px or Qy
        }
    }
}

extern "C" void kernel_launch(void* const* d_in, const int* in_sizes, int n_in,
                              void* d_out, int out_size, void* d_ws, size_t ws_size,
                              hipStream_t stream) {
    const float* x  = (const float*)d_in[0];
    const float* h1 = (const float*)d_in[1];
    const float* c1 = (const float*)d_in[2];
    const float* w1 = (const float*)d_in[3];
    const float* h2 = (const float*)d_in[4];
    const float* c2 = (const float*)d_in[5];
    const float* w2 = (const float*)d_in[6];
    const float* h3 = (const float*)d_in[7];
    const float* c3 = (const float*)d_in[8];
    const float* w3 = (const float*)d_in[9];

    hipMemsetAsync(d_out, 0, (size_t)out_size * sizeof(float), stream);

    // 3 sets x 8 center-chunks x 32 point-blocks = 768 blocks (3/CU)
    srbf_main<<<dim3(768), dim3(256), 0, stream>>>(
        x, h1, c1, w1, h2, c2, w2, h3, c3, w3, (float*)d_out);
}